// Round 12
// baseline (170.098 us; speedup 1.0000x reference)
//
#include <hip/hip_runtime.h>
#include <hip/hip_bf16.h>

#define BETA_LOG2E 14.426950408889634f   // 10 * log2(e)
#define EPSN 1e-6f

typedef __bf16 bf16x8 __attribute__((ext_vector_type(8)));
typedef float  f32x4  __attribute__((ext_vector_type(4)));

static __device__ inline unsigned short f2bf(float f) {
    __hip_bfloat16 h = __float2bfloat16(f);
    return __builtin_bit_cast(unsigned short, h);
}
static __device__ inline float bf2f(unsigned short u) {
    unsigned int b = ((unsigned int)u) << 16;
    return __builtin_bit_cast(float, b);
}

// ---------------------------------------------------------------------------
// Kernel 1 (round-11, passing, absmax 0.125): L2-normalize over C, transpose
// [b][c][n] -> [b][n][c], bf16; queries pre-scaled by BETA_LOG2E (folds into
// the existing scale multiply -- rounding count unchanged).
// ---------------------------------------------------------------------------
__global__ __launch_bounds__(256) void k_norm_transpose(
    const float* __restrict__ f0, const float* __restrict__ f1,
    unsigned short* __restrict__ aT, unsigned short* __restrict__ bT)
{
    __shared__ unsigned short tile[32 * 256];  // [n][c] raw bf16
    __shared__ float partial[32][32];          // [cg][n]
    __shared__ float inv_l[32];

    int idx   = blockIdx.x;
    int which = idx >> 9;
    int rem   = idx & 511;
    int b     = rem >> 7;
    int n0    = (rem & 127) * 32;
    const float* src = which ? f1 : f0;
    unsigned short* dst = which ? bT : aT;
    float scale = which ? 1.0f : BETA_LOG2E;   // queries carry beta*log2(e)

    int t  = threadIdx.x;
    int nq = t & 7;     // 8 quads of 4 n  -> 32 n
    int cg = t >> 3;    // 32 groups of 8 c -> 256 c

    const float* sp = src + ((size_t)(b * 256 + cg * 8)) * 4096 + n0 + nq * 4;

    f32x4 ss = {0.f, 0.f, 0.f, 0.f};
    unsigned int pk[4][4];   // [j = n sub-row][4 uints = 8 bf16 over c]
#pragma unroll
    for (int i = 0; i < 8; ++i) {
        f32x4 v = *reinterpret_cast<const f32x4*>(sp + (size_t)i * 4096);
        ss += v * v;
#pragma unroll
        for (int j = 0; j < 4; ++j) {
            unsigned int h = f2bf(v[j]);
            if (i & 1) pk[j][i >> 1] |= h << 16;
            else       pk[j][i >> 1]  = h;
        }
    }
#pragma unroll
    for (int j = 0; j < 4; ++j) {
        int n = nq * 4 + j;
        *reinterpret_cast<uint4*>(&tile[n * 256 + cg * 8]) =
            *reinterpret_cast<const uint4*>(pk[j]);
    }
    *reinterpret_cast<f32x4*>(&partial[cg][nq * 4]) = ss;
    __syncthreads();
    if (t < 32) {
        float s = 0.f;
#pragma unroll
        for (int k = 0; k < 32; ++k) s += partial[k][t];
        inv_l[t] = scale / fmaxf(sqrtf(s), EPSN);
    }
    __syncthreads();

#pragma unroll
    for (int it = 0; it < 4; ++it) {
        int n  = it * 8 + (t >> 5);
        int cb = t & 31;
        uint4 v = *reinterpret_cast<const uint4*>(&tile[n * 256 + cb * 8]);
        float inv = inv_l[n];
        unsigned int o[4];
#pragma unroll
        for (int k = 0; k < 4; ++k) {
            unsigned int u = (&v.x)[k];
            unsigned short lo = f2bf(bf2f((unsigned short)(u & 0xffffu)) * inv);
            unsigned short hi = f2bf(bf2f((unsigned short)(u >> 16)) * inv);
            o[k] = (unsigned int)lo | ((unsigned int)hi << 16);
        }
        *reinterpret_cast<uint4*>(&dst[((size_t)(b * 4096 + n0 + n)) * 256 + cb * 8]) =
            *reinterpret_cast<const uint4*>(o);
    }
}

// ---------------------------------------------------------------------------
// Kernel 2 v13: 64 QUERIES PER WAVE (4 A-strips). Per-CU LDS-read floor
// halves (each bfrag feeds 4 MFMAs, was 2): LDS was the largest pipe floor
// (49k cy + 16k conflicts of a 126k budget). Staging/DMA/swizzle and the
// Abel/prescale epilogue are byte-identical to v12 (both validated).
// Grid 512 = 4b x 16qt(256q) x 8ks(512k); 2 blocks/CU, 128KB LDS.
// __launch_bounds__(256,2): VGPR cap 256 (afrag 128 + state 64 + misc).
// stats[q][ks8] = {Z, Sx, Sy, Pmax}
// ---------------------------------------------------------------------------
__global__ __launch_bounds__(256, 2) void k_flash(
    const unsigned short* __restrict__ aT, const unsigned short* __restrict__ bT,
    float* __restrict__ stats)
{
    __shared__ unsigned short kb[2 * 64 * 256];   // 64 KB double-buffered

    int idx   = blockIdx.x;
    int xcd   = idx & 7;                 // XCD swizzle: batch -> 2 XCDs
    int batch = xcd >> 1;
    int sub   = ((idx >> 3) << 1) | (xcd & 1);   // [0,64)
    int qt    = sub >> 2;                // [0,16)
    int ks    = sub & 3;                 // hold: need 8 ks -> recompute below
    // remap: sub in [0,64) = qt16 x ks... use 16 qt x 4? We need 128 subs for
    // 16qt x 8ks -> grid 1024? No: grid 512 => sub in [0,128) required.
    // Fix: sub = ((idx >> 3) << 1) | (xcd & 1) gives [0,128) for idx<512. OK:
    sub   = ((idx >> 3) << 1) | (xcd & 1);       // [0,128)
    qt    = sub >> 3;                    // [0,16)
    ks    = sub & 7;                     // [0,8)

    int t    = threadIdx.x;
    int w    = t >> 6;
    int lane = t & 63;
    int quad = lane >> 4;
    int l15  = lane & 15;
    int q0w  = qt * 256 + w * 64;
    int k0   = ks * 512;

    // resident A fragments: 4 strips of 16 queries x 8 K-steps (128 VGPR)
    bf16x8 afrag[4][8];
#pragma unroll
    for (int s = 0; s < 4; ++s) {
        const unsigned short* ap =
            aT + ((size_t)(batch * 4096 + q0w + s * 16 + l15)) * 256 + quad * 8;
#pragma unroll
        for (int kk = 0; kk < 8; ++kk)
            afrag[s][kk] = *reinterpret_cast<const bf16x8*>(ap + kk * 32);
    }

    // swizzled read offsets: logical blk = quad+4kk stored at blk^(key&7)
    int s7 = l15 & 7;
    int offs[8];
#pragma unroll
    for (int kk = 0; kk < 8; ++kk) offs[kk] = (((quad + 4 * kk) ^ s7) << 3);

    // staging: wave w, iter i covers key = i*8 + 2w + (lane>>5), block lane&31.
    int krem = 2 * w + (lane >> 5);
    int goff = krem * 256 + (((lane & 31) ^ (krem & 7)) << 3);

    float Z[16], V[16], U[16], Sm[16];
#pragma unroll
    for (int i = 0; i < 16; ++i) { Z[i] = 0.f; V[i] = 0.f; U[i] = 0.f; Sm[i] = -1e30f; }

    const unsigned short* gkbase = bT + ((size_t)(batch * 4096 + k0)) * 256;

#define STAGE(CH, BUFHW)                                                        \
    {                                                                           \
        const unsigned short* gsp = gkbase + (size_t)(CH) * 16384 + goff;       \
        unsigned short* lp0 = kb + (BUFHW) + w * 512;                           \
        _Pragma("unroll")                                                       \
        for (int i = 0; i < 8; ++i)                                             \
            __builtin_amdgcn_global_load_lds(                                   \
                (const __attribute__((address_space(1))) void*)(gsp + i * 2048),\
                (__attribute__((address_space(3))) void*)(lp0 + i * 2048),      \
                16, 0, 0);                                                      \
    }

    STAGE(0, 0);
    __syncthreads();                     // implicit vmcnt(0): buf0 ready
    int bufOff = 0;

    for (int ch = 0; ch < 8; ++ch) {
        if (ch < 7) STAGE(ch + 1, bufOff ^ 16384);   // DMA hides under compute

#pragma unroll
        for (int nt = 0; nt < 4; ++nt) {
            f32x4 acc0 = {0.f, 0.f, 0.f, 0.f};
            f32x4 acc1 = {0.f, 0.f, 0.f, 0.f};
            f32x4 acc2 = {0.f, 0.f, 0.f, 0.f};
            f32x4 acc3 = {0.f, 0.f, 0.f, 0.f};
            const unsigned short* lp = kb + bufOff + (nt * 16 + l15) * 256;
#pragma unroll
            for (int kk = 0; kk < 8; ++kk) {
                bf16x8 bfrag = *reinterpret_cast<const bf16x8*>(lp + offs[kk]);
                acc0 = __builtin_amdgcn_mfma_f32_16x16x32_bf16(afrag[0][kk], bfrag, acc0, 0, 0, 0);
                acc1 = __builtin_amdgcn_mfma_f32_16x16x32_bf16(afrag[1][kk], bfrag, acc1, 0, 0, 0);
                acc2 = __builtin_amdgcn_mfma_f32_16x16x32_bf16(afrag[2][kk], bfrag, acc2, 0, 0, 0);
                acc3 = __builtin_amdgcn_mfma_f32_16x16x32_bf16(afrag[3][kk], bfrag, acc3, 0, 0, 0);
            }
            // acc is already beta*log2e*cos (A pre-scaled): 3 VALU per score
#pragma unroll
            for (int r = 0; r < 4; ++r) {
                float p0 = exp2f(acc0[r]);
                Z[r]      += p0;  Sm[r]      = fmaxf(Sm[r],      acc0[r]);
                float p1 = exp2f(acc1[r]);
                Z[4 + r]  += p1;  Sm[4 + r]  = fmaxf(Sm[4 + r],  acc1[r]);
                float p2 = exp2f(acc2[r]);
                Z[8 + r]  += p2;  Sm[8 + r]  = fmaxf(Sm[8 + r],  acc2[r]);
                float p3 = exp2f(acc3[r]);
                Z[12 + r] += p3;  Sm[12 + r] = fmaxf(Sm[12 + r], acc3[r]);
            }
            if (nt < 3) {
#pragma unroll
                for (int i = 0; i < 16; ++i) V[i] += Z[i];   // Abel for Sx
            }
        }
#pragma unroll
        for (int i = 0; i < 16; ++i) U[i] += Z[i];           // Abel for Sy
        __syncthreads();   // drains ch+1 DMA (vmcnt0) + all reads of buf done
        bufOff ^= 16384;
    }
#undef STAGE

    // per-lane Sx prefix, then reduce across the 16 col-lanes
    float l15f = (float)l15;
#pragma unroll
    for (int i = 0; i < 16; ++i) V[i] = l15f * Z[i] - 16.0f * V[i];

#pragma unroll
    for (int i = 0; i < 16; ++i) {
#pragma unroll
        for (int m = 1; m <= 8; m <<= 1) {
            Z[i]  += __shfl_xor(Z[i], m);
            V[i]  += __shfl_xor(V[i], m);
            U[i]  += __shfl_xor(U[i], m);
            Sm[i]  = fmaxf(Sm[i], __shfl_xor(Sm[i], m));
        }
    }
    if (l15 == 0) {
        float kyc = 8.0f * (float)(ks + 1);        // (y0 + C) = 8ks + 8
#pragma unroll
        for (int s = 0; s < 4; ++s)
#pragma unroll
            for (int r = 0; r < 4; ++r) {
                int q = q0w + s * 16 + quad * 4 + r;   // C/D row = quad*4+reg
                int i = s * 4 + r;
                float Sx = V[i] + 48.0f * U[i];        // l15-prefix + 48U
                float Sy = kyc * Z[i] - U[i];          // (8ks+8)Z - U
                f32x4 st = {Z[i], Sx, Sy, exp2f(Sm[i])};
                *reinterpret_cast<f32x4*>(&stats[((size_t)(batch * 4096 + q) * 8 + ks) * 4]) = st;
            }
    }
}

// ---------------------------------------------------------------------------
// Kernel 3 (round-5, passing): merge 8 key-splits, write warp then cert.
// ---------------------------------------------------------------------------
__global__ __launch_bounds__(256) void k_finalize(
    const float* __restrict__ stats, float* __restrict__ out)
{
    int q = blockIdx.x * 256 + threadIdx.x;   // [0, 16384)
    const f32x4* s = reinterpret_cast<const f32x4*>(stats + (size_t)q * 32);
    float Z = 0.f, Sx = 0.f, Sy = 0.f, Pm = 0.f;
#pragma unroll
    for (int k = 0; k < 8; ++k) {
        f32x4 a = s[k];
        Z += a.x; Sx += a.y; Sy += a.z; Pm = fmaxf(Pm, a.w);
    }
    float invZ = 1.0f / Z;
    out[q * 2 + 0]  = Sx * invZ;
    out[q * 2 + 1]  = Sy * invZ;
    out[32768 + q]  = Pm * invZ;
}

extern "C" void kernel_launch(void* const* d_in, const int* in_sizes, int n_in,
                              void* d_out, int out_size, void* d_ws, size_t ws_size,
                              hipStream_t stream)
{
    const float* f0 = (const float*)d_in[0];
    const float* f1 = (const float*)d_in[1];
    unsigned short* aT = (unsigned short*)d_ws;           // 8 MB
    unsigned short* bT = aT + (size_t)4 * 4096 * 256;     // 8 MB
    float* stats = (float*)(bT + (size_t)4 * 4096 * 256); // 16384*8*4 f32 = 2 MB
    float* out = (float*)d_out;

    hipLaunchKernelGGL(k_norm_transpose, dim3(1024), dim3(256), 0, stream, f0, f1, aT, bT);
    hipLaunchKernelGGL(k_flash,          dim3(512),  dim3(256), 0, stream, aT, bT, stats);
    hipLaunchKernelGGL(k_finalize,       dim3(64),   dim3(256), 0, stream, stats, out);
}

// Round 13
// 137.404 us; speedup vs baseline: 1.2379x; 1.2379x over previous
//
#include <hip/hip_runtime.h>
#include <hip/hip_bf16.h>

#define BETA_LOG2E 14.426950408889634f   // 10 * log2(e)
#define EPSN 1e-6f

typedef __bf16 bf16x8 __attribute__((ext_vector_type(8)));
typedef float  f32x4  __attribute__((ext_vector_type(4)));

static __device__ inline unsigned short f2bf(float f) {
    __hip_bfloat16 h = __float2bfloat16(f);
    return __builtin_bit_cast(unsigned short, h);
}
static __device__ inline float bf2f(unsigned short u) {
    unsigned int b = ((unsigned int)u) << 16;
    return __builtin_bit_cast(float, b);
}

// ---------------------------------------------------------------------------
// Kernel 1 (round-11, passing, absmax 0.125): L2-normalize over C, transpose
// [b][c][n] -> [b][n][c], bf16; queries pre-scaled by BETA_LOG2E.
// ---------------------------------------------------------------------------
__global__ __launch_bounds__(256) void k_norm_transpose(
    const float* __restrict__ f0, const float* __restrict__ f1,
    unsigned short* __restrict__ aT, unsigned short* __restrict__ bT)
{
    __shared__ unsigned short tile[32 * 256];  // [n][c] raw bf16
    __shared__ float partial[32][32];          // [cg][n]
    __shared__ float inv_l[32];

    int idx   = blockIdx.x;
    int which = idx >> 9;
    int rem   = idx & 511;
    int b     = rem >> 7;
    int n0    = (rem & 127) * 32;
    const float* src = which ? f1 : f0;
    unsigned short* dst = which ? bT : aT;
    float scale = which ? 1.0f : BETA_LOG2E;   // queries carry beta*log2(e)

    int t  = threadIdx.x;
    int nq = t & 7;     // 8 quads of 4 n  -> 32 n
    int cg = t >> 3;    // 32 groups of 8 c -> 256 c

    const float* sp = src + ((size_t)(b * 256 + cg * 8)) * 4096 + n0 + nq * 4;

    f32x4 ss = {0.f, 0.f, 0.f, 0.f};
    unsigned int pk[4][4];   // [j = n sub-row][4 uints = 8 bf16 over c]
#pragma unroll
    for (int i = 0; i < 8; ++i) {
        f32x4 v = *reinterpret_cast<const f32x4*>(sp + (size_t)i * 4096);
        ss += v * v;
#pragma unroll
        for (int j = 0; j < 4; ++j) {
            unsigned int h = f2bf(v[j]);
            if (i & 1) pk[j][i >> 1] |= h << 16;
            else       pk[j][i >> 1]  = h;
        }
    }
#pragma unroll
    for (int j = 0; j < 4; ++j) {
        int n = nq * 4 + j;
        *reinterpret_cast<uint4*>(&tile[n * 256 + cg * 8]) =
            *reinterpret_cast<const uint4*>(pk[j]);
    }
    *reinterpret_cast<f32x4*>(&partial[cg][nq * 4]) = ss;
    __syncthreads();
    if (t < 32) {
        float s = 0.f;
#pragma unroll
        for (int k = 0; k < 32; ++k) s += partial[k][t];
        inv_l[t] = scale / fmaxf(sqrtf(s), EPSN);
    }
    __syncthreads();

#pragma unroll
    for (int it = 0; it < 4; ++it) {
        int n  = it * 8 + (t >> 5);
        int cb = t & 31;
        uint4 v = *reinterpret_cast<const uint4*>(&tile[n * 256 + cb * 8]);
        float inv = inv_l[n];
        unsigned int o[4];
#pragma unroll
        for (int k = 0; k < 4; ++k) {
            unsigned int u = (&v.x)[k];
            unsigned short lo = f2bf(bf2f((unsigned short)(u & 0xffffu)) * inv);
            unsigned short hi = f2bf(bf2f((unsigned short)(u >> 16)) * inv);
            o[k] = (unsigned int)lo | ((unsigned int)hi << 16);
        }
        *reinterpret_cast<uint4*>(&dst[((size_t)(b * 4096 + n0 + n)) * 256 + cb * 8]) =
            *reinterpret_cast<const uint4*>(o);
    }
}

// ---------------------------------------------------------------------------
// Kernel 2 v14: round-12 body (64q/wave, CORRECT: absmax 0.125) with ONE
// change: __launch_bounds__(256, 1). r12's (256,2) made the compiler cap at
// 128 VGPR and spill ~100 regs (WRITE 70MB). (256,1) lifts the budget to 512;
// the ~230 actually needed allocates spill-free, and HARDWARE occupancy is set
// by the real count (230 <= 256 -> 2 waves/SIMD -> the 2 blocks/CU the grid
// needs). Single-variable A/B vs r12 on the regalloc theory.
// Grid 512 = 4b x 16qt(256q) x 8ks(512k); 64KB LDS dbuf; DMA staging.
// stats[q][ks8] = {Z, Sx, Sy, Pmax}
// ---------------------------------------------------------------------------
__global__ __launch_bounds__(256, 1) void k_flash(
    const unsigned short* __restrict__ aT, const unsigned short* __restrict__ bT,
    float* __restrict__ stats)
{
    __shared__ unsigned short kb[2 * 64 * 256];   // 64 KB double-buffered

    int idx   = blockIdx.x;
    int xcd   = idx & 7;                 // XCD swizzle: batch -> 2 XCDs
    int batch = xcd >> 1;
    int sub   = ((idx >> 3) << 1) | (xcd & 1);   // [0,128)
    int qt    = sub >> 3;                // [0,16)
    int ks    = sub & 7;                 // [0,8)

    int t    = threadIdx.x;
    int w    = t >> 6;
    int lane = t & 63;
    int quad = lane >> 4;
    int l15  = lane & 15;
    int q0w  = qt * 256 + w * 64;
    int k0   = ks * 512;

    // resident A fragments: 4 strips of 16 queries x 8 K-steps (128 VGPR)
    bf16x8 afrag[4][8];
#pragma unroll
    for (int s = 0; s < 4; ++s) {
        const unsigned short* ap =
            aT + ((size_t)(batch * 4096 + q0w + s * 16 + l15)) * 256 + quad * 8;
#pragma unroll
        for (int kk = 0; kk < 8; ++kk)
            afrag[s][kk] = *reinterpret_cast<const bf16x8*>(ap + kk * 32);
    }

    // swizzled read offsets: logical blk = quad+4kk stored at blk^(key&7)
    int s7 = l15 & 7;
    int offs[8];
#pragma unroll
    for (int kk = 0; kk < 8; ++kk) offs[kk] = (((quad + 4 * kk) ^ s7) << 3);

    // staging: wave w, iter i covers key = i*8 + 2w + (lane>>5), block lane&31.
    int krem = 2 * w + (lane >> 5);
    int goff = krem * 256 + (((lane & 31) ^ (krem & 7)) << 3);

    float Z[16], V[16], U[16], Sm[16];
#pragma unroll
    for (int i = 0; i < 16; ++i) { Z[i] = 0.f; V[i] = 0.f; U[i] = 0.f; Sm[i] = -1e30f; }

    const unsigned short* gkbase = bT + ((size_t)(batch * 4096 + k0)) * 256;

#define STAGE(CH, BUFHW)                                                        \
    {                                                                           \
        const unsigned short* gsp = gkbase + (size_t)(CH) * 16384 + goff;       \
        unsigned short* lp0 = kb + (BUFHW) + w * 512;                           \
        _Pragma("unroll")                                                       \
        for (int i = 0; i < 8; ++i)                                             \
            __builtin_amdgcn_global_load_lds(                                   \
                (const __attribute__((address_space(1))) void*)(gsp + i * 2048),\
                (__attribute__((address_space(3))) void*)(lp0 + i * 2048),      \
                16, 0, 0);                                                      \
    }

    STAGE(0, 0);
    __syncthreads();                     // implicit vmcnt(0): buf0 ready
    int bufOff = 0;

    for (int ch = 0; ch < 8; ++ch) {
        if (ch < 7) STAGE(ch + 1, bufOff ^ 16384);   // DMA hides under compute

#pragma unroll
        for (int nt = 0; nt < 4; ++nt) {
            f32x4 acc0 = {0.f, 0.f, 0.f, 0.f};
            f32x4 acc1 = {0.f, 0.f, 0.f, 0.f};
            f32x4 acc2 = {0.f, 0.f, 0.f, 0.f};
            f32x4 acc3 = {0.f, 0.f, 0.f, 0.f};
            const unsigned short* lp = kb + bufOff + (nt * 16 + l15) * 256;
#pragma unroll
            for (int kk = 0; kk < 8; ++kk) {
                bf16x8 bfrag = *reinterpret_cast<const bf16x8*>(lp + offs[kk]);
                acc0 = __builtin_amdgcn_mfma_f32_16x16x32_bf16(afrag[0][kk], bfrag, acc0, 0, 0, 0);
                acc1 = __builtin_amdgcn_mfma_f32_16x16x32_bf16(afrag[1][kk], bfrag, acc1, 0, 0, 0);
                acc2 = __builtin_amdgcn_mfma_f32_16x16x32_bf16(afrag[2][kk], bfrag, acc2, 0, 0, 0);
                acc3 = __builtin_amdgcn_mfma_f32_16x16x32_bf16(afrag[3][kk], bfrag, acc3, 0, 0, 0);
            }
            // acc is already beta*log2e*cos (A pre-scaled): 3 VALU per score
#pragma unroll
            for (int r = 0; r < 4; ++r) {
                float p0 = exp2f(acc0[r]);
                Z[r]      += p0;  Sm[r]      = fmaxf(Sm[r],      acc0[r]);
                float p1 = exp2f(acc1[r]);
                Z[4 + r]  += p1;  Sm[4 + r]  = fmaxf(Sm[4 + r],  acc1[r]);
                float p2 = exp2f(acc2[r]);
                Z[8 + r]  += p2;  Sm[8 + r]  = fmaxf(Sm[8 + r],  acc2[r]);
                float p3 = exp2f(acc3[r]);
                Z[12 + r] += p3;  Sm[12 + r] = fmaxf(Sm[12 + r], acc3[r]);
            }
            if (nt < 3) {
#pragma unroll
                for (int i = 0; i < 16; ++i) V[i] += Z[i];   // Abel for Sx
            }
        }
#pragma unroll
        for (int i = 0; i < 16; ++i) U[i] += Z[i];           // Abel for Sy
        __syncthreads();   // drains ch+1 DMA (vmcnt0) + all reads of buf done
        bufOff ^= 16384;
    }
#undef STAGE

    // per-lane Sx prefix, then reduce across the 16 col-lanes
    float l15f = (float)l15;
#pragma unroll
    for (int i = 0; i < 16; ++i) V[i] = l15f * Z[i] - 16.0f * V[i];

#pragma unroll
    for (int i = 0; i < 16; ++i) {
#pragma unroll
        for (int m = 1; m <= 8; m <<= 1) {
            Z[i]  += __shfl_xor(Z[i], m);
            V[i]  += __shfl_xor(V[i], m);
            U[i]  += __shfl_xor(U[i], m);
            Sm[i]  = fmaxf(Sm[i], __shfl_xor(Sm[i], m));
        }
    }
    if (l15 == 0) {
        float kyc = 8.0f * (float)(ks + 1);        // (y0 + C) = 8ks + 8
#pragma unroll
        for (int s = 0; s < 4; ++s)
#pragma unroll
            for (int r = 0; r < 4; ++r) {
                int q = q0w + s * 16 + quad * 4 + r;   // C/D row = quad*4+reg
                int i = s * 4 + r;
                float Sx = V[i] + 48.0f * U[i];        // l15-prefix + 48U
                float Sy = kyc * Z[i] - U[i];          // (8ks+8)Z - U
                f32x4 st = {Z[i], Sx, Sy, exp2f(Sm[i])};
                *reinterpret_cast<f32x4*>(&stats[((size_t)(batch * 4096 + q) * 8 + ks) * 4]) = st;
            }
    }
}

// ---------------------------------------------------------------------------
// Kernel 3 (round-5, passing): merge 8 key-splits, write warp then cert.
// ---------------------------------------------------------------------------
__global__ __launch_bounds__(256) void k_finalize(
    const float* __restrict__ stats, float* __restrict__ out)
{
    int q = blockIdx.x * 256 + threadIdx.x;   // [0, 16384)
    const f32x4* s = reinterpret_cast<const f32x4*>(stats + (size_t)q * 32);
    float Z = 0.f, Sx = 0.f, Sy = 0.f, Pm = 0.f;
#pragma unroll
    for (int k = 0; k < 8; ++k) {
        f32x4 a = s[k];
        Z += a.x; Sx += a.y; Sy += a.z; Pm = fmaxf(Pm, a.w);
    }
    float invZ = 1.0f / Z;
    out[q * 2 + 0]  = Sx * invZ;
    out[q * 2 + 1]  = Sy * invZ;
    out[32768 + q]  = Pm * invZ;
}

extern "C" void kernel_launch(void* const* d_in, const int* in_sizes, int n_in,
                              void* d_out, int out_size, void* d_ws, size_t ws_size,
                              hipStream_t stream)
{
    const float* f0 = (const float*)d_in[0];
    const float* f1 = (const float*)d_in[1];
    unsigned short* aT = (unsigned short*)d_ws;           // 8 MB
    unsigned short* bT = aT + (size_t)4 * 4096 * 256;     // 8 MB
    float* stats = (float*)(bT + (size_t)4 * 4096 * 256); // 16384*8*4 f32 = 2 MB
    float* out = (float*)d_out;

    hipLaunchKernelGGL(k_norm_transpose, dim3(1024), dim3(256), 0, stream, f0, f1, aT, bT);
    hipLaunchKernelGGL(k_flash,          dim3(512),  dim3(256), 0, stream, aT, bT, stats);
    hipLaunchKernelGGL(k_finalize,       dim3(64),   dim3(256), 0, stream, stats, out);
}

// Round 14
// 129.238 us; speedup vs baseline: 1.3162x; 1.0632x over previous
//
#include <hip/hip_runtime.h>
#include <hip/hip_bf16.h>

#define BETA_LOG2E 14.426950408889634f   // 10 * log2(e)
#define EPSN 1e-6f

typedef __bf16 bf16x8 __attribute__((ext_vector_type(8)));
typedef float  f32x4  __attribute__((ext_vector_type(4)));

static __device__ inline unsigned short f2bf(float f) {
    __hip_bfloat16 h = __float2bfloat16(f);
    return __builtin_bit_cast(unsigned short, h);
}
static __device__ inline float bf2f(unsigned short u) {
    unsigned int b = ((unsigned int)u) << 16;
    return __builtin_bit_cast(float, b);
}

// ---------------------------------------------------------------------------
// Kernel 1a (round-3, hardware-verified): sum-of-squares partials, PURE
// STREAMING (1KB contiguous segments/wave-instr). Non-atomic slab split.
// ssp[slab 8][which 2][b 4][n 4096]. grid 1024 = 2 x 4b x 8 cslab x 16 nspan.
// ---------------------------------------------------------------------------
__global__ __launch_bounds__(256) void k_norm_ss(
    const float* __restrict__ f0, const float* __restrict__ f1,
    float* __restrict__ ssp)
{
    __shared__ f32x4 partial[4][64];

    int idx   = blockIdx.x;
    int which = idx >> 9;
    int rem   = idx & 511;
    int b     = rem >> 7;
    int cs    = (rem >> 4) & 7;
    int ns    = rem & 15;
    const float* src = which ? f1 : f0;

    int t  = threadIdx.x;
    int i  = t & 63;    // n4 index (wave-contiguous -> 1KB segments)
    int cr = t >> 6;    // 4 row groups
    int n0 = ns * 256;

    const float* sp = src + ((size_t)(b * 256 + cs * 32 + cr)) * 4096 + n0 + i * 4;

    f32x4 ss = {0.f, 0.f, 0.f, 0.f};
#pragma unroll
    for (int j = 0; j < 8; ++j) {
        f32x4 v = *reinterpret_cast<const f32x4*>(sp + (size_t)j * 4 * 4096);
        ss += v * v;
    }
    partial[cr][i] = ss;
    __syncthreads();
    if (t < 64) {
        f32x4 s4 = partial[0][t] + partial[1][t] + partial[2][t] + partial[3][t];
        size_t g = (size_t)cs * 32768 + which * 16384 + b * 4096 + n0 + t * 4;
        *reinterpret_cast<f32x4*>(&ssp[g]) = s4;
    }
}

// ---------------------------------------------------------------------------
// Kernel 1b (round-3, hardware-verified; + r11 prescale): transpose + scale,
// reading f0/f1 L3-WARM (pass 1 touched all 33MB << 256MB L3) with 1KB/row
// segments. LDS XOR swizzle blk' = blk ^ ((c>>3)&7): conflict-free b128
// writes AND u32 gather reads. Queries (f0->aT) pre-scaled by BETA_LOG2E
// (folds into inv_l -- rounding count unchanged, validated r11).
// grid 512 = 2 tensor x 4 b x 16 ntile x 4 ctile.
// ---------------------------------------------------------------------------
__global__ __launch_bounds__(256) void k_transpose_scale(
    const float* __restrict__ f0, const float* __restrict__ f1,
    const float* __restrict__ ssp,
    unsigned short* __restrict__ aT, unsigned short* __restrict__ bT)
{
    __shared__ unsigned short tile[64 * 256];  // 32KB: [c][256 n], swizzled 16B blocks
    __shared__ float inv_l[256];

    int idx   = blockIdx.x;
    int which = idx >> 8;
    int rem   = idx & 255;
    int b     = rem >> 6;
    int nt    = (rem >> 2) & 15;
    int ct    = rem & 3;
    const float* src = which ? f1 : f0;
    unsigned short* dst = which ? bT : aT;
    float scale = which ? 1.0f : BETA_LOG2E;

    int t  = threadIdx.x;
    int n0 = nt * 256;
    int c0 = ct * 64;

    // per-n inverse norms from the 8 slab partials
    {
        int gn = which * 16384 + b * 4096 + n0 + t;
        float s = 0.f;
#pragma unroll
        for (int sl = 0; sl < 8; ++sl) s += ssp[sl * 32768 + gn];
        inv_l[t] = scale / fmaxf(sqrtf(s), EPSN);
    }

    // stage: thread (i32 = n8 idx, c8 = row octet); rows c = c8*8 + j.
    // 1KB global segments per row-visit; b128 LDS writes, blk' = i32 ^ c8.
    int i32 = t & 31;
    int c8  = t >> 5;
    const float* gp = src + ((size_t)(b * 256 + c0 + c8 * 8)) * 4096 + n0 + i32 * 8;
#pragma unroll
    for (int j = 0; j < 8; ++j) {
        f32x4 va = *reinterpret_cast<const f32x4*>(gp + (size_t)j * 4096);
        f32x4 vb = *reinterpret_cast<const f32x4*>(gp + (size_t)j * 4096 + 4);
        unsigned int pk[4];
        pk[0] = (unsigned int)f2bf(va[0]) | ((unsigned int)f2bf(va[1]) << 16);
        pk[1] = (unsigned int)f2bf(va[2]) | ((unsigned int)f2bf(va[3]) << 16);
        pk[2] = (unsigned int)f2bf(vb[0]) | ((unsigned int)f2bf(vb[1]) << 16);
        pk[3] = (unsigned int)f2bf(vb[2]) | ((unsigned int)f2bf(vb[3]) << 16);
        int c   = c8 * 8 + j;
        int blk = i32 ^ c8;                    // c8 == (c>>3)&7
        *reinterpret_cast<uint4*>(&tile[c * 256 + blk * 8]) =
            *reinterpret_cast<const uint4*>(pk);
    }
    __syncthreads();

    // gather-out: thread cg = t&7 owns c = cg*8..+7 (contiguous 16B store);
    // u32 reads pick an n-pair; banks spread by blk = (n>>3)^cg.
    int cg = t & 7;
#pragma unroll
    for (int iter = 0; iter < 4; ++iter) {
        int n   = iter * 64 + (t >> 3) * 2;    // even
        float ivA = inv_l[n], ivB = inv_l[n + 1];
        unsigned int oA[4], oB[4];
#pragma unroll
        for (int j = 0; j < 8; ++j) {
            int c   = cg * 8 + j;
            int blk = (n >> 3) ^ cg;           // cg == (c>>3)&7
            unsigned int u = *reinterpret_cast<const unsigned int*>(
                &tile[c * 256 + blk * 8 + (n & 7)]);
            unsigned short hA = f2bf(bf2f((unsigned short)(u & 0xffffu)) * ivA);
            unsigned short hB = f2bf(bf2f((unsigned short)(u >> 16)) * ivB);
            if (j & 1) { oA[j >> 1] |= ((unsigned int)hA) << 16;
                         oB[j >> 1] |= ((unsigned int)hB) << 16; }
            else       { oA[j >> 1]  = hA;  oB[j >> 1]  = hB; }
        }
        size_t base = ((size_t)(b * 4096 + n0 + n)) * 256 + c0 + cg * 8;
        *reinterpret_cast<uint4*>(&dst[base])       = *reinterpret_cast<const uint4*>(oA);
        *reinterpret_cast<uint4*>(&dst[base + 256]) = *reinterpret_cast<const uint4*>(oB);
    }
}

// ---------------------------------------------------------------------------
// Kernel 2 (round-11 VERBATIM, 52.7us proven): flash cosine-sim, DMA staging
// via global_load_lds, LDS dbuf 2x32KB, 1 barrier/chunk, XOR swizzle;
// pre-scaled A (no per-score mul) + Abel Sx/Sy + pre-exp Sm.
// 32q/wave @ 116 VGPR is the structural optimum (r12/r13: 64q falsified --
// VGPR tier drops waves/SIMD 4->2 and loses more than LDS-read halving gains).
// stats[q][ks4] = {Z, Sx, Sy, Pmax}
// ---------------------------------------------------------------------------
__global__ __launch_bounds__(256) void k_flash(
    const unsigned short* __restrict__ aT, const unsigned short* __restrict__ bT,
    float* __restrict__ stats)
{
    __shared__ unsigned short kb[2 * 64 * 256];   // 64 KB double-buffered

    int idx   = blockIdx.x;
    int xcd   = idx & 7;                 // XCD swizzle: batch -> 2 XCDs
    int batch = xcd >> 1;
    int sub   = ((idx >> 3) << 1) | (xcd & 1);   // [0,128)
    int qt    = sub >> 2;                // [0,32)
    int ks    = sub & 3;                 // [0,4)

    int t    = threadIdx.x;
    int w    = t >> 6;
    int lane = t & 63;
    int quad = lane >> 4;
    int l15  = lane & 15;
    int q0w  = qt * 128 + w * 32;
    int k0   = ks * 1024;

    // resident A fragments: 2 strips of 16 queries x 8 K-steps
    bf16x8 afrag[2][8];
#pragma unroll
    for (int s = 0; s < 2; ++s) {
        const unsigned short* ap =
            aT + ((size_t)(batch * 4096 + q0w + s * 16 + l15)) * 256 + quad * 8;
#pragma unroll
        for (int kk = 0; kk < 8; ++kk)
            afrag[s][kk] = *reinterpret_cast<const bf16x8*>(ap + kk * 32);
    }

    // swizzled read offsets: logical blk = quad+4kk stored at blk^(key&7)
    int s7 = l15 & 7;
    int offs[8];
#pragma unroll
    for (int kk = 0; kk < 8; ++kk) offs[kk] = (((quad + 4 * kk) ^ s7) << 3);

    // staging: wave w, iter i covers key = i*8 + 2w + (lane>>5), block lane&31.
    int krem = 2 * w + (lane >> 5);
    int goff = krem * 256 + (((lane & 31) ^ (krem & 7)) << 3);

    float Z[8], V[8], U[8], Sm[8];
#pragma unroll
    for (int i = 0; i < 8; ++i) { Z[i] = 0.f; V[i] = 0.f; U[i] = 0.f; Sm[i] = -1e30f; }

    const unsigned short* gkbase = bT + ((size_t)(batch * 4096 + k0)) * 256;

#define STAGE(CH, BUFHW)                                                        \
    {                                                                           \
        const unsigned short* gsp = gkbase + (size_t)(CH) * 16384 + goff;       \
        unsigned short* lp0 = kb + (BUFHW) + w * 512;                           \
        _Pragma("unroll")                                                       \
        for (int i = 0; i < 8; ++i)                                             \
            __builtin_amdgcn_global_load_lds(                                   \
                (const __attribute__((address_space(1))) void*)(gsp + i * 2048),\
                (__attribute__((address_space(3))) void*)(lp0 + i * 2048),      \
                16, 0, 0);                                                      \
    }

    STAGE(0, 0);
    __syncthreads();                     // implicit vmcnt(0): buf0 ready
    int bufOff = 0;

    for (int ch = 0; ch < 16; ++ch) {
        if (ch < 15) STAGE(ch + 1, bufOff ^ 16384);   // DMA hides under compute

#pragma unroll
        for (int nt = 0; nt < 4; ++nt) {
            f32x4 acc0 = {0.f, 0.f, 0.f, 0.f};
            f32x4 acc1 = {0.f, 0.f, 0.f, 0.f};
            const unsigned short* lp = kb + bufOff + (nt * 16 + l15) * 256;
#pragma unroll
            for (int kk = 0; kk < 8; ++kk) {
                bf16x8 bfrag = *reinterpret_cast<const bf16x8*>(lp + offs[kk]);
                acc0 = __builtin_amdgcn_mfma_f32_16x16x32_bf16(afrag[0][kk], bfrag, acc0, 0, 0, 0);
                acc1 = __builtin_amdgcn_mfma_f32_16x16x32_bf16(afrag[1][kk], bfrag, acc1, 0, 0, 0);
            }
            // acc is already beta*log2e*cos (A pre-scaled): 3 VALU per score
#pragma unroll
            for (int r = 0; r < 4; ++r) {
                float p0 = exp2f(acc0[r]);
                Z[r]  += p0;
                Sm[r]  = fmaxf(Sm[r], acc0[r]);
                float p1 = exp2f(acc1[r]);
                Z[4 + r]  += p1;
                Sm[4 + r]  = fmaxf(Sm[4 + r], acc1[r]);
            }
            if (nt < 3) {
#pragma unroll
                for (int i = 0; i < 8; ++i) V[i] += Z[i];   // Abel for Sx
            }
        }
#pragma unroll
        for (int i = 0; i < 8; ++i) U[i] += Z[i];           // Abel for Sy
        __syncthreads();   // drains ch+1 DMA (vmcnt0) + all reads of buf done
        bufOff ^= 16384;
    }
#undef STAGE

    // per-lane Sx prefix, then reduce across the 16 col-lanes
    float l15f = (float)l15;
#pragma unroll
    for (int i = 0; i < 8; ++i) V[i] = l15f * Z[i] - 16.0f * V[i];

#pragma unroll
    for (int i = 0; i < 8; ++i) {
#pragma unroll
        for (int m = 1; m <= 8; m <<= 1) {
            Z[i]  += __shfl_xor(Z[i], m);
            V[i]  += __shfl_xor(V[i], m);
            U[i]  += __shfl_xor(U[i], m);
            Sm[i]  = fmaxf(Sm[i], __shfl_xor(Sm[i], m));
        }
    }
    if (l15 == 0) {
        float kyc = 16.0f * (float)(ks + 1);
#pragma unroll
        for (int s = 0; s < 2; ++s)
#pragma unroll
            for (int r = 0; r < 4; ++r) {
                int q = q0w + s * 16 + quad * 4 + r;   // C/D row = quad*4+reg
                int i = s * 4 + r;
                float Sx = V[i] + 48.0f * U[i];        // l15-prefix + 48U
                float Sy = kyc * Z[i] - U[i];          // 16(ks+1)Z - U
                f32x4 st = {Z[i], Sx, Sy, exp2f(Sm[i])};
                *reinterpret_cast<f32x4*>(&stats[((size_t)(batch * 4096 + q) * 4 + ks) * 4]) = st;
            }
    }
}

// ---------------------------------------------------------------------------
// Kernel 3 (round-0, passing): merge 4 key-splits, write warp then cert.
// ---------------------------------------------------------------------------
__global__ __launch_bounds__(256) void k_finalize(
    const float* __restrict__ stats, float* __restrict__ out)
{
    int q = blockIdx.x * 256 + threadIdx.x;   // [0, 16384)
    const f32x4* s = reinterpret_cast<const f32x4*>(stats + (size_t)q * 16);
    f32x4 a0 = s[0], a1 = s[1], a2 = s[2], a3 = s[3];
    float Z  = a0.x + a1.x + a2.x + a3.x;
    float Sx = a0.y + a1.y + a2.y + a3.y;
    float Sy = a0.z + a1.z + a2.z + a3.z;
    float Pm = fmaxf(fmaxf(a0.w, a1.w), fmaxf(a2.w, a3.w));
    float invZ = 1.0f / Z;
    out[q * 2 + 0]  = Sx * invZ;
    out[q * 2 + 1]  = Sy * invZ;
    out[32768 + q]  = Pm * invZ;
}

extern "C" void kernel_launch(void* const* d_in, const int* in_sizes, int n_in,
                              void* d_out, int out_size, void* d_ws, size_t ws_size,
                              hipStream_t stream)
{
    const float* f0 = (const float*)d_in[0];
    const float* f1 = (const float*)d_in[1];
    unsigned short* aT = (unsigned short*)d_ws;           // 8 MB
    unsigned short* bT = aT + (size_t)4 * 4096 * 256;     // 8 MB
    float* stats = (float*)(bT + (size_t)4 * 4096 * 256); // 16384*4*4 f32 = 1 MB
    float* ssp   = stats + (size_t)16384 * 16;            // 1 MB (8 slabs x 32768)
    float* out = (float*)d_out;

    hipLaunchKernelGGL(k_norm_ss,         dim3(1024), dim3(256), 0, stream, f0, f1, ssp);
    hipLaunchKernelGGL(k_transpose_scale, dim3(512),  dim3(256), 0, stream, f0, f1, ssp, aT, bT);
    hipLaunchKernelGGL(k_flash,           dim3(512),  dim3(256), 0, stream, aT, bT, stats);
    hipLaunchKernelGGL(k_finalize,        dim3(64),   dim3(256), 0, stream, stats, out);
}

// Round 15
// 121.538 us; speedup vs baseline: 1.3995x; 1.0634x over previous
//
#include <hip/hip_runtime.h>
#include <hip/hip_bf16.h>

#define BETA_LOG2E 14.426950408889634f   // 10 * log2(e)
#define EPSN 1e-6f

typedef __bf16 bf16x8 __attribute__((ext_vector_type(8)));
typedef float  f32x4  __attribute__((ext_vector_type(4)));

static __device__ inline unsigned short f2bf(float f) {
    __hip_bfloat16 h = __float2bfloat16(f);
    return __builtin_bit_cast(unsigned short, h);
}
static __device__ inline float bf2f(unsigned short u) {
    unsigned int b = ((unsigned int)u) << 16;
    return __builtin_bit_cast(float, b);
}

// ---------------------------------------------------------------------------
// Kernel 1 (round-11 body, best measured): L2-normalize over C, transpose
// [b][c][n] -> [b][n][c], bf16; queries pre-scaled by BETA_LOG2E.
// NEW (r15): XCD-aligned block remap -- batch b's producers run on XCD pair
// {2b, 2b+1}, the same XCDs whose flash blocks consume aT/bT for batch b
// (flash: batch = (idx&7)>>1). Pure bijection of the same 1024 work items:
// idx&7 = 2b+half selects XCD; idx>>3 carries which (1b) + 64 ntile-pairs.
// ---------------------------------------------------------------------------
__global__ __launch_bounds__(256) void k_norm_transpose(
    const float* __restrict__ f0, const float* __restrict__ f1,
    unsigned short* __restrict__ aT, unsigned short* __restrict__ bT)
{
    __shared__ unsigned short tile[32 * 256];  // [n][c] raw bf16
    __shared__ float partial[32][32];          // [cg][n]
    __shared__ float inv_l[32];

    int idx   = blockIdx.x;
    int xcd   = idx & 7;
    int b     = xcd >> 1;                  // batch -> XCD pair {2b, 2b+1}
    int half  = xcd & 1;
    int hi    = idx >> 3;                  // [0,128)
    int which = hi >> 6;                   // {0,1}
    int n0    = (((hi & 63) << 1) | half) * 32;   // 128 ntiles of 32 n
    const float* src = which ? f1 : f0;
    unsigned short* dst = which ? bT : aT;
    float scale = which ? 1.0f : BETA_LOG2E;   // queries carry beta*log2(e)

    int t  = threadIdx.x;
    int nq = t & 7;     // 8 quads of 4 n  -> 32 n
    int cg = t >> 3;    // 32 groups of 8 c -> 256 c

    const float* sp = src + ((size_t)(b * 256 + cg * 8)) * 4096 + n0 + nq * 4;

    f32x4 ss = {0.f, 0.f, 0.f, 0.f};
    unsigned int pk[4][4];   // [j = n sub-row][4 uints = 8 bf16 over c]
#pragma unroll
    for (int i = 0; i < 8; ++i) {
        f32x4 v = *reinterpret_cast<const f32x4*>(sp + (size_t)i * 4096);
        ss += v * v;
#pragma unroll
        for (int j = 0; j < 4; ++j) {
            unsigned int h = f2bf(v[j]);
            if (i & 1) pk[j][i >> 1] |= h << 16;
            else       pk[j][i >> 1]  = h;
        }
    }
#pragma unroll
    for (int j = 0; j < 4; ++j) {
        int n = nq * 4 + j;
        *reinterpret_cast<uint4*>(&tile[n * 256 + cg * 8]) =
            *reinterpret_cast<const uint4*>(pk[j]);
    }
    *reinterpret_cast<f32x4*>(&partial[cg][nq * 4]) = ss;
    __syncthreads();
    if (t < 32) {
        float s = 0.f;
#pragma unroll
        for (int k = 0; k < 32; ++k) s += partial[k][t];
        inv_l[t] = scale / fmaxf(sqrtf(s), EPSN);
    }
    __syncthreads();

#pragma unroll
    for (int it = 0; it < 4; ++it) {
        int n  = it * 8 + (t >> 5);
        int cb = t & 31;
        uint4 v = *reinterpret_cast<const uint4*>(&tile[n * 256 + cb * 8]);
        float inv = inv_l[n];
        unsigned int o[4];
#pragma unroll
        for (int k = 0; k < 4; ++k) {
            unsigned int u = (&v.x)[k];
            unsigned short lo = f2bf(bf2f((unsigned short)(u & 0xffffu)) * inv);
            unsigned short hi2 = f2bf(bf2f((unsigned short)(u >> 16)) * inv);
            o[k] = (unsigned int)lo | ((unsigned int)hi2 << 16);
        }
        *reinterpret_cast<uint4*>(&dst[((size_t)(b * 4096 + n0 + n)) * 256 + cb * 8]) =
            *reinterpret_cast<const uint4*>(o);
    }
}

// ---------------------------------------------------------------------------
// Kernel 2 (round-11 VERBATIM, 52.7us session-best): flash cosine-sim.
// DMA staging via global_load_lds (zero staging VGPRs), LDS dbuf 2x32KB,
// 1 barrier/chunk, XOR swizzle; pre-scaled A (no per-score mul) + Abel Sx/Sy
// + pre-exp Sm. 32q/wave @ 116 VGPR is the structural optimum (64q falsified:
// VGPR tier halves wave slots and loses more than LDS-read halving gains).
// stats[q][ks4] = {Z, Sx, Sy, Pmax}
// ---------------------------------------------------------------------------
__global__ __launch_bounds__(256) void k_flash(
    const unsigned short* __restrict__ aT, const unsigned short* __restrict__ bT,
    float* __restrict__ stats)
{
    __shared__ unsigned short kb[2 * 64 * 256];   // 64 KB double-buffered

    int idx   = blockIdx.x;
    int xcd   = idx & 7;                 // XCD swizzle: batch -> 2 XCDs
    int batch = xcd >> 1;
    int sub   = ((idx >> 3) << 1) | (xcd & 1);   // [0,128)
    int qt    = sub >> 2;                // [0,32)
    int ks    = sub & 3;                 // [0,4)

    int t    = threadIdx.x;
    int w    = t >> 6;
    int lane = t & 63;
    int quad = lane >> 4;
    int l15  = lane & 15;
    int q0w  = qt * 128 + w * 32;
    int k0   = ks * 1024;

    // resident A fragments: 2 strips of 16 queries x 8 K-steps
    bf16x8 afrag[2][8];
#pragma unroll
    for (int s = 0; s < 2; ++s) {
        const unsigned short* ap =
            aT + ((size_t)(batch * 4096 + q0w + s * 16 + l15)) * 256 + quad * 8;
#pragma unroll
        for (int kk = 0; kk < 8; ++kk)
            afrag[s][kk] = *reinterpret_cast<const bf16x8*>(ap + kk * 32);
    }

    // swizzled read offsets: logical blk = quad+4kk stored at blk^(key&7)
    int s7 = l15 & 7;
    int offs[8];
#pragma unroll
    for (int kk = 0; kk < 8; ++kk) offs[kk] = (((quad + 4 * kk) ^ s7) << 3);

    // staging: wave w, iter i covers key = i*8 + 2w + (lane>>5), block lane&31.
    int krem = 2 * w + (lane >> 5);
    int goff = krem * 256 + (((lane & 31) ^ (krem & 7)) << 3);

    float Z[8], V[8], U[8], Sm[8];
#pragma unroll
    for (int i = 0; i < 8; ++i) { Z[i] = 0.f; V[i] = 0.f; U[i] = 0.f; Sm[i] = -1e30f; }

    const unsigned short* gkbase = bT + ((size_t)(batch * 4096 + k0)) * 256;

#define STAGE(CH, BUFHW)                                                        \
    {                                                                           \
        const unsigned short* gsp = gkbase + (size_t)(CH) * 16384 + goff;       \
        unsigned short* lp0 = kb + (BUFHW) + w * 512;                           \
        _Pragma("unroll")                                                       \
        for (int i = 0; i < 8; ++i)                                             \
            __builtin_amdgcn_global_load_lds(                                   \
                (const __attribute__((address_space(1))) void*)(gsp + i * 2048),\
                (__attribute__((address_space(3))) void*)(lp0 + i * 2048),      \
                16, 0, 0);                                                      \
    }

    STAGE(0, 0);
    __syncthreads();                     // implicit vmcnt(0): buf0 ready
    int bufOff = 0;

    for (int ch = 0; ch < 16; ++ch) {
        if (ch < 15) STAGE(ch + 1, bufOff ^ 16384);   // DMA hides under compute

#pragma unroll
        for (int nt = 0; nt < 4; ++nt) {
            f32x4 acc0 = {0.f, 0.f, 0.f, 0.f};
            f32x4 acc1 = {0.f, 0.f, 0.f, 0.f};
            const unsigned short* lp = kb + bufOff + (nt * 16 + l15) * 256;
#pragma unroll
            for (int kk = 0; kk < 8; ++kk) {
                bf16x8 bfrag = *reinterpret_cast<const bf16x8*>(lp + offs[kk]);
                acc0 = __builtin_amdgcn_mfma_f32_16x16x32_bf16(afrag[0][kk], bfrag, acc0, 0, 0, 0);
                acc1 = __builtin_amdgcn_mfma_f32_16x16x32_bf16(afrag[1][kk], bfrag, acc1, 0, 0, 0);
            }
            // acc is already beta*log2e*cos (A pre-scaled): 3 VALU per score
#pragma unroll
            for (int r = 0; r < 4; ++r) {
                float p0 = exp2f(acc0[r]);
                Z[r]  += p0;
                Sm[r]  = fmaxf(Sm[r], acc0[r]);
                float p1 = exp2f(acc1[r]);
                Z[4 + r]  += p1;
                Sm[4 + r]  = fmaxf(Sm[4 + r], acc1[r]);
            }
            if (nt < 3) {
#pragma unroll
                for (int i = 0; i < 8; ++i) V[i] += Z[i];   // Abel for Sx
            }
        }
#pragma unroll
        for (int i = 0; i < 8; ++i) U[i] += Z[i];           // Abel for Sy
        __syncthreads();   // drains ch+1 DMA (vmcnt0) + all reads of buf done
        bufOff ^= 16384;
    }
#undef STAGE

    // per-lane Sx prefix, then reduce across the 16 col-lanes
    float l15f = (float)l15;
#pragma unroll
    for (int i = 0; i < 8; ++i) V[i] = l15f * Z[i] - 16.0f * V[i];

#pragma unroll
    for (int i = 0; i < 8; ++i) {
#pragma unroll
        for (int m = 1; m <= 8; m <<= 1) {
            Z[i]  += __shfl_xor(Z[i], m);
            V[i]  += __shfl_xor(V[i], m);
            U[i]  += __shfl_xor(U[i], m);
            Sm[i]  = fmaxf(Sm[i], __shfl_xor(Sm[i], m));
        }
    }
    if (l15 == 0) {
        float kyc = 16.0f * (float)(ks + 1);
#pragma unroll
        for (int s = 0; s < 2; ++s)
#pragma unroll
            for (int r = 0; r < 4; ++r) {
                int q = q0w + s * 16 + quad * 4 + r;   // C/D row = quad*4+reg
                int i = s * 4 + r;
                float Sx = V[i] + 48.0f * U[i];        // l15-prefix + 48U
                float Sy = kyc * Z[i] - U[i];          // 16(ks+1)Z - U
                f32x4 st = {Z[i], Sx, Sy, exp2f(Sm[i])};
                *reinterpret_cast<f32x4*>(&stats[((size_t)(batch * 4096 + q) * 4 + ks) * 4]) = st;
            }
    }
}

// ---------------------------------------------------------------------------
// Kernel 3 (round-0, passing): merge 4 key-splits, write warp then cert.
// ---------------------------------------------------------------------------
__global__ __launch_bounds__(256) void k_finalize(
    const float* __restrict__ stats, float* __restrict__ out)
{
    int q = blockIdx.x * 256 + threadIdx.x;   // [0, 16384)
    const f32x4* s = reinterpret_cast<const f32x4*>(stats + (size_t)q * 16);
    f32x4 a0 = s[0], a1 = s[1], a2 = s[2], a3 = s[3];
    float Z  = a0.x + a1.x + a2.x + a3.x;
    float Sx = a0.y + a1.y + a2.y + a3.y;
    float Sy = a0.z + a1.z + a2.z + a3.z;
    float Pm = fmaxf(fmaxf(a0.w, a1.w), fmaxf(a2.w, a3.w));
    float invZ = 1.0f / Z;
    out[q * 2 + 0]  = Sx * invZ;
    out[q * 2 + 1]  = Sy * invZ;
    out[32768 + q]  = Pm * invZ;
}

extern "C" void kernel_launch(void* const* d_in, const int* in_sizes, int n_in,
                              void* d_out, int out_size, void* d_ws, size_t ws_size,
                              hipStream_t stream)
{
    const float* f0 = (const float*)d_in[0];
    const float* f1 = (const float*)d_in[1];
    unsigned short* aT = (unsigned short*)d_ws;           // 8 MB
    unsigned short* bT = aT + (size_t)4 * 4096 * 256;     // 8 MB
    float* stats = (float*)(bT + (size_t)4 * 4096 * 256); // 16384*4*4 f32 = 1 MB
    float* out = (float*)d_out;

    hipLaunchKernelGGL(k_norm_transpose, dim3(1024), dim3(256), 0, stream, f0, f1, aT, bT);
    hipLaunchKernelGGL(k_flash,          dim3(512),  dim3(256), 0, stream, aT, bT, stats);
    hipLaunchKernelGGL(k_finalize,       dim3(64),   dim3(256), 0, stream, stats, out);
}